// Round 4
// baseline (667.948 us; speedup 1.0000x reference)
//
#include <hip/hip_runtime.h>
#include <math.h>

#define NSEQ 4096
#define EDIM 512
#define NHEAD 8
#define DHEAD 64

// LESSON (R4, R8): direct-from-global MFMA fragment loads regress vs
// LDS-staged ds_read_b128 fragments, even when perfectly coalesced/tiled.
// LESSON (R10/R14): bigger K-chunks (BK=128 gemm, 256-key attn) regress --
// LDS size/occupancy and conflicts beat barrier-amortization on this chip.
// LESSON (R11/R12): attention was LDS-traffic bound THEN; wider per-wave
// q-tiles (64 q/wave) cut fragment re-reads 2x (53->46us).
// LESSON (R13): folding fp32 casts into GEMM staging regresses ~18us.
// LESSON (R15/R16): kernel deletion and traffic de-duplication pay exactly
// their traffic cost (~4us each). Harness re-poison (~45us fillBuffer) fixed.
// R17: rowsum via VALU adds + shfl_xor instead of ones-MFMA.
// R18: attention on 32x32x16 MFMA, in-register P via cvt_pkrtz +
// v_permlane32_swap_b32 (T12). LDS conflicts 5.8M->0.5M, inner LDS halved.
// R19: epilogue granularity fix (permlane-swapped us8 stores, 32B/row/instr;
// TCC partial-write RMW gone): attn 60->44.4us.
// R20: double-buffer + 1 barrier/chunk: 44.4->42.7us only. Revised model:
// mfma32 = 32 cyc/SIMD -> MFMA 32% + VALU ~28% + LDS ~30% ~= fully
// serialized chain, zero pipe overlap. TLP-starved at 2 waves/SIMD
// (grid-capped 512 blocks).
// R21: split-K 8 -> 1024 blocks = 4 blocks/CU = 4 waves/SIMD (regime:
// latency-bound, all pipes <35% -> occupancy now pays). Single-buffer LDS
// (35840B, 4 blocks fit) + reg-prefetch one chunk ahead. T5 setprio around
// MFMA clusters. Costs +32MB Zp/combine traffic (~5us), needs 51MB ws ->
// runtime ws_size guard with split-4 fallback.

typedef unsigned short ushort_t;
typedef __attribute__((ext_vector_type(8))) _Float16 half8;    // 8 f16 (4 VGPRs)
typedef __attribute__((ext_vector_type(2))) __fp16 pkhalf2;    // cvt_pkrtz out
typedef __attribute__((ext_vector_type(4))) float floatx4;     // MFMA C/D 16x16
typedef __attribute__((ext_vector_type(16))) float floatx16;   // MFMA C/D 32x32
typedef __attribute__((ext_vector_type(8))) ushort_t us8;
typedef __attribute__((ext_vector_type(4))) ushort_t us4;

#define C2SCALE 0.02254211f  // log2(e)/64, folded into Q at projection

__device__ __forceinline__ ushort_t f2h(float x) {  // RNE float->f16
  union { _Float16 h; ushort_t u; } v;
  v.h = (_Float16)x;
  return v.u;
}

#if __has_builtin(__builtin_amdgcn_exp2f)
#define EXP2F(x) __builtin_amdgcn_exp2f(x)
#else
#define EXP2F(x) exp2f(x)
#endif

// ---------------------------------------------------------------------------
// fused fp32 -> f16 cast for inp (2048 blocks) + 4 weight mats (1024 blocks)
// ---------------------------------------------------------------------------
__global__ __launch_bounds__(256) void cast_all(
    const float* __restrict__ inp, ushort_t* __restrict__ Xf,
    const float* __restrict__ w0, const float* __restrict__ w1,
    const float* __restrict__ w2, const float* __restrict__ w3,
    ushort_t* __restrict__ d0, ushort_t* __restrict__ d1,
    ushort_t* __restrict__ d2, ushort_t* __restrict__ d3) {
  const int bid = blockIdx.x;
  const float* s;
  ushort_t* d;
  int blk;
  if (bid < 2048) {
    s = inp; d = Xf; blk = bid;
  } else {
    const int seg = (bid - 2048) >> 8;
    blk = (bid - 2048) & 255;
    switch (seg) {
      case 0: s = w0; d = d0; break;
      case 1: s = w1; d = d1; break;
      case 2: s = w2; d = d2; break;
      default: s = w3; d = d3; break;
    }
  }
  const int i = (blk * 256 + threadIdx.x) * 4;
  const float4 v = *(const float4*)(s + i);
  us4 o;
  o[0] = f2h(v.x); o[1] = f2h(v.y); o[2] = f2h(v.z); o[3] = f2h(v.w);
  *(us4*)(d + i) = o;
}

// ---------------------------------------------------------------------------
// Fused QKV single-plane f16 MFMA NT GEMM, LDS-staged, BK=64, 3 blocks/CU.
// 64o x 128n tile.
// z=0: Q -> f16 (E,N) scaled by C2SCALE.   z=1: K -> f16 (N,E).
// z=2: V -> f16 Vt[h][d][m] DIRECTLY (strided n-tile; see R15).
// ---------------------------------------------------------------------------
__global__ __launch_bounds__(256, 3) void gemm_qkv(
    const ushort_t* __restrict__ WQf, const float* __restrict__ WQb,
    const ushort_t* __restrict__ WKf, const float* __restrict__ WKb,
    const ushort_t* __restrict__ WVf, const float* __restrict__ WVb,
    const ushort_t* __restrict__ Xf, ushort_t* __restrict__ Qb,
    ushort_t* __restrict__ Kb, ushort_t* __restrict__ Vt) {
  __shared__ __align__(16) char smem[27648];
  ushort_t(*Ws)[72] = (ushort_t(*)[72])smem;           // [64][72]
  ushort_t(*Xs)[72] = (ushort_t(*)[72])(smem + 9216);  // [128][72]

  const int tid = threadIdx.x;
  const int w = tid >> 6, lane = tid & 63, quad = lane >> 4, l16 = lane & 15;
  const int o0 = blockIdx.y * 64, n0 = blockIdx.x * 128, z = blockIdx.z;
  const int wr = tid >> 2, wseg = (tid & 3) * 16;  // W stage: 64 rows x 16 k
  const int xr = tid >> 1, xseg = (tid & 1) * 32;  // X stage: 128 rows x 32 k
  const int xrow = (z == 2)
                       ? ((xr >> 1) * 64 + blockIdx.x * 2 + (xr & 1))
                       : (n0 + xr);

  const ushort_t* Wf = (z == 0) ? WQf : (z == 1) ? WKf : WVf;
  const float* bias = (z == 0) ? WQb : (z == 1) ? WKb : WVb;

  floatx4 acc[4][2];
#pragma unroll
  for (int ot = 0; ot < 4; ++ot)
#pragma unroll
    for (int nt = 0; nt < 2; ++nt) {
      acc[ot][nt][0] = 0.f; acc[ot][nt][1] = 0.f;
      acc[ot][nt][2] = 0.f; acc[ot][nt][3] = 0.f;
    }

  for (int k0 = 0; k0 < EDIM; k0 += 64) {
    const us8 w0 = *(const us8*)(Wf + (o0 + wr) * 512 + k0 + wseg);
    const us8 w1 = *(const us8*)(Wf + (o0 + wr) * 512 + k0 + wseg + 8);
    us8 xv[4];
#pragma unroll
    for (int j = 0; j < 4; ++j)
      xv[j] = *(const us8*)(Xf + xrow * 512 + k0 + xseg + j * 8);
    __syncthreads();  // previous iteration's LDS reads complete
    *(us8*)&Ws[wr][wseg] = w0;
    *(us8*)&Ws[wr][wseg + 8] = w1;
#pragma unroll
    for (int j = 0; j < 4; ++j) *(us8*)&Xs[xr][xseg + j * 8] = xv[j];
    __syncthreads();

    half8 a[2][4], b[2][2];
#pragma unroll
    for (int kh = 0; kh < 2; ++kh) {
#pragma unroll
      for (int ot = 0; ot < 4; ++ot)
        a[kh][ot] = *(const half8*)&Ws[ot * 16 + l16][kh * 32 + quad * 8];
#pragma unroll
      for (int nt = 0; nt < 2; ++nt)
        b[kh][nt] =
            *(const half8*)&Xs[w * 32 + nt * 16 + l16][kh * 32 + quad * 8];
    }
#pragma unroll
    for (int kh = 0; kh < 2; ++kh)
#pragma unroll
      for (int ot = 0; ot < 4; ++ot)
#pragma unroll
        for (int nt = 0; nt < 2; ++nt)
          acc[ot][nt] = __builtin_amdgcn_mfma_f32_16x16x32_f16(
              a[kh][ot], b[kh][nt], acc[ot][nt], 0, 0, 0);
  }

  __syncthreads();  // staging reads done; smem reused for epilogue
  float bo[4][4];
#pragma unroll
  for (int ot = 0; ot < 4; ++ot)
#pragma unroll
    for (int r = 0; r < 4; ++r)
      bo[ot][r] = bias[o0 + ot * 16 + quad * 4 + r];

  if (z == 0) {  // Q: f16 (E,N), scaled
    ushort_t(*Cs)[136] = (ushort_t(*)[136])smem;
#pragma unroll
    for (int ot = 0; ot < 4; ++ot)
#pragma unroll
      for (int nt = 0; nt < 2; ++nt)
#pragma unroll
        for (int r = 0; r < 4; ++r)
          Cs[ot * 16 + quad * 4 + r][w * 32 + nt * 16 + l16] =
              f2h((acc[ot][nt][r] + bo[ot][r]) * C2SCALE);
    __syncthreads();
    const int row = tid >> 2, seg = (tid & 3) * 32;
#pragma unroll
    for (int j = 0; j < 4; ++j)
      *(us8*)(Qb + (o0 + row) * 4096 + n0 + seg + j * 8) =
          *(const us8*)&Cs[row][seg + j * 8];
  } else if (z == 1) {  // K: f16 (N,E)
    ushort_t(*Cs)[72] = (ushort_t(*)[72])smem;
#pragma unroll
    for (int ot = 0; ot < 4; ++ot)
#pragma unroll
      for (int nt = 0; nt < 2; ++nt)
#pragma unroll
        for (int r = 0; r < 4; ++r)
          Cs[w * 32 + nt * 16 + l16][ot * 16 + quad * 4 + r] =
              f2h(acc[ot][nt][r] + bo[ot][r]);
    __syncthreads();
    const int row = tid >> 1, seg = (tid & 1) * 32;
#pragma unroll
    for (int j = 0; j < 4; ++j)
      *(us8*)(Kb + (n0 + row) * 512 + o0 + seg + j * 8) =
          *(const us8*)&Cs[row][seg + j * 8];
  } else {  // V: emit Vt[h][d][m] directly
    ushort_t(*Cs)[72] = (ushort_t(*)[72])smem;  // [local n][o-local]
#pragma unroll
    for (int ot = 0; ot < 4; ++ot)
#pragma unroll
      for (int nt = 0; nt < 2; ++nt)
#pragma unroll
        for (int r = 0; r < 4; ++r)
          Cs[w * 32 + nt * 16 + l16][ot * 16 + quad * 4 + r] =
              f2h(acc[ot][nt][r] + bo[ot][r]);
    __syncthreads();
    const int h = blockIdx.y;
    const int d0 = blockIdx.x * 2;
#pragma unroll
    for (int t = 0; t < 4; ++t) {
      const int c = tid + t * 256;   // 0..1023 us8-chunks
      const int oo = c >> 4;         // 0..63
      const int dd = (c >> 3) & 1;
      const int g = c & 7;           // nh-group of 8
      us8 v;
#pragma unroll
      for (int j = 0; j < 8; ++j) v[j] = Cs[(g * 8 + j) * 2 + dd][oo];
      *(us8*)(Vt + h * 262144 + (d0 + dd) * 4096 + oo * 64 + g * 8) = v;
    }
  }
}

// ---------------------------------------------------------------------------
// combine: Zf[n][e] = (sum_z Zp[z][n][e]) / (sum_z Lp[z][h][n]), f16 out.
// ---------------------------------------------------------------------------
template <int SPL>
__global__ __launch_bounds__(256) void combine(const ushort_t* __restrict__ Zp,
                                               const float* __restrict__ Lp,
                                               ushort_t* __restrict__ Zf) {
  const int base = (blockIdx.x * 256 + threadIdx.x) * 8;
  const int n = base >> 9, e = base & 511, h = e >> 6;
  float lsum = 0.f;
  float va[8];
#pragma unroll
  for (int j = 0; j < 8; ++j) va[j] = 0.f;
#pragma unroll
  for (int zz = 0; zz < SPL; ++zz) {
    const half8 v = *(const half8*)(Zp + zz * 2097152 + base);
#pragma unroll
    for (int j = 0; j < 8; ++j) va[j] += (float)v[j];
    lsum += Lp[zz * 32768 + h * 4096 + n];
  }
  const float inv = 1.0f / lsum;
  us8 o;
#pragma unroll
  for (int j = 0; j < 8; ++j) o[j] = f2h(va[j] * inv);
  *(us8*)(Zf + base) = o;
}

// ---------------------------------------------------------------------------
// Output projection: f16 W and Zf from LDS, fp32 (N,E) out. BK=64,
// 64o x 64n tile, 512 blocks.
// ---------------------------------------------------------------------------
__global__ __launch_bounds__(256, 2) void gemm_out(
    const ushort_t* __restrict__ Wf, const ushort_t* __restrict__ Zf,
    const float* __restrict__ bias, float* __restrict__ C) {
  __shared__ __align__(16) char smem[18432];
  ushort_t(*Ws)[72] = (ushort_t(*)[72])smem;           // [64][72]
  ushort_t(*Xs)[72] = (ushort_t(*)[72])(smem + 9216);  // [64][72]

  const int tid = threadIdx.x;
  const int w = tid >> 6, lane = tid & 63, quad = lane >> 4, l16 = lane & 15;
  const int o0 = blockIdx.y * 64, n0 = blockIdx.x * 64;
  const int lr = tid >> 2, lseg = (tid & 3) * 16;

  floatx4 acc[4];
#pragma unroll
  for (int ot = 0; ot < 4; ++ot) {
    acc[ot][0] = 0.f; acc[ot][1] = 0.f; acc[ot][2] = 0.f; acc[ot][3] = 0.f;
  }

  for (int k0 = 0; k0 < EDIM; k0 += 64) {
    const us8 w0 = *(const us8*)(Wf + (o0 + lr) * 512 + k0 + lseg);
    const us8 w1 = *(const us8*)(Wf + (o0 + lr) * 512 + k0 + lseg + 8);
    const us8 x0 = *(const us8*)(Zf + (n0 + lr) * 512 + k0 + lseg);
    const us8 x1 = *(const us8*)(Zf + (n0 + lr) * 512 + k0 + lseg + 8);
    __syncthreads();
    *(us8*)&Ws[lr][lseg] = w0;
    *(us8*)&Ws[lr][lseg + 8] = w1;
    *(us8*)&Xs[lr][lseg] = x0;
    *(us8*)&Xs[lr][lseg + 8] = x1;
    __syncthreads();

    half8 a[2][4], b[2];
#pragma unroll
    for (int kh = 0; kh < 2; ++kh) {
#pragma unroll
      for (int ot = 0; ot < 4; ++ot)
        a[kh][ot] = *(const half8*)&Ws[ot * 16 + l16][kh * 32 + quad * 8];
      b[kh] = *(const half8*)&Xs[w * 16 + l16][kh * 32 + quad * 8];
    }
#pragma unroll
    for (int kh = 0; kh < 2; ++kh)
#pragma unroll
      for (int ot = 0; ot < 4; ++ot)
        acc[ot] = __builtin_amdgcn_mfma_f32_16x16x32_f16(a[kh][ot], b[kh],
                                                         acc[ot], 0, 0, 0);
  }

  __syncthreads();
  float(*Cs)[68] = (float(*)[68])smem;
#pragma unroll
  for (int ot = 0; ot < 4; ++ot) {
    floatx4 v = acc[ot];
#pragma unroll
    for (int r = 0; r < 4; ++r) v[r] += bias[o0 + ot * 16 + quad * 4 + r];
    *(floatx4*)&Cs[w * 16 + l16][ot * 16 + quad * 4] = v;
  }
  __syncthreads();
  const int row = tid >> 2, seg = (tid & 3) * 16;
#pragma unroll
  for (int j = 0; j < 4; ++j)
    *(float4*)(C + (n0 + row) * 512 + o0 + seg + j * 4) =
        *(const float4*)&Cs[row][seg + j * 4];
}

// ---------------------------------------------------------------------------
// Flash attention, R21: 32x32x16 f16 MFMA, transposed-score, single-buffer
// LDS K/V with one-chunk-ahead register prefetch, in-register P (cvt_pkrtz
// + v_permlane32_swap_b32), us8-granular Z^T partials, split-K SPL,
// 4 blocks/CU (__launch_bounds__(256,4), LDS 35840).
//   QK:  s = mfma32(kf, qf)    D[col=q=l32][row=m=(r&3)+8*(r>>2)+4*hi]
//   PV:  z = mfma32(vf, pa)    D[col=q=l32][row=d-local]
// Schedule per chunk c: [compute buf from LDS] [barrier] [STOREC regs(c+1)]
// [LOADC(c+2)] [barrier]. Loads land a full compute phase before their
// STOREC consumes them; with 4 blocks/CU the barriers overlap across blocks.
// ---------------------------------------------------------------------------
template <int SPL>
__global__ __launch_bounds__(256, 4) void attn_mfma(
    const ushort_t* __restrict__ Qb, const ushort_t* __restrict__ Kb,
    const ushort_t* __restrict__ Vt, ushort_t* __restrict__ Zp,
    float* __restrict__ Lp) {
  __shared__ __align__(16) ushort_t Ks[128][72];    // K chunk [m][d]
  __shared__ __align__(16) ushort_t Vts[64][136];   // V^T chunk [d][m]
  constexpr int NCH = (NSEQ / SPL) / 128;

  const int tid = threadIdx.x;
  const int w = tid >> 6;
  const int lane = tid & 63;
  const int hi = lane >> 5;
  const int l32 = lane & 31;
  const int h = blockIdx.y;
  const int n0 = blockIdx.x * 256;
  const int z = blockIdx.z;
  const int mbase = z * (NSEQ / SPL);

  // Q fragments: B-operand, B[col=q=l32][k=d=kk*16+hi*8+j]
  half8 qf[2][4];
#pragma unroll
  for (int qt = 0; qt < 2; ++qt) {
    const ushort_t* qsrc =
        Qb + h * 262144 + (n0 + w * 64 + qt * 32 + l32) * 64 + hi * 8;
#pragma unroll
    for (int kk = 0; kk < 4; ++kk)
      qf[qt][kk] = *(const half8*)(qsrc + kk * 16);
  }

  floatx16 zacc[2][2];
  float sl[2] = {0.f, 0.f};
#pragma unroll
  for (int qt = 0; qt < 2; ++qt)
#pragma unroll
    for (int dt = 0; dt < 2; ++dt)
#pragma unroll
      for (int r = 0; r < 16; ++r) zacc[qt][dt][r] = 0.f;

  const int kr = tid >> 2;
  const int kc = (tid & 3) << 4;
  const int vd = tid >> 2;
  const int vm = (tid & 3) << 5;
  const ushort_t* kbase = Kb + h * 262144 + mbase * 64;
  const ushort_t* vbase = Vt + h * 262144 + vd * 4096 + mbase + vm;

  us8 kst[4], vst[4];

#define LOADC(c)                                                       \
  {                                                                    \
    const ushort_t* ksrc = kbase + (c) * (128 * 64);                   \
    kst[0] = *(const us8*)(ksrc + kr * 64 + kc);                       \
    kst[1] = *(const us8*)(ksrc + kr * 64 + kc + 8);                   \
    kst[2] = *(const us8*)(ksrc + (64 + kr) * 64 + kc);                \
    kst[3] = *(const us8*)(ksrc + (64 + kr) * 64 + kc + 8);            \
    const ushort_t* vsrc = vbase + (c) * 128;                          \
    _Pragma("unroll") for (int j = 0; j < 4; ++j) vst[j] =             \
        *(const us8*)(vsrc + j * 8);                                   \
  }

#define STOREC()                                                       \
  {                                                                    \
    *(us8*)&Ks[kr][kc] = kst[0];                                       \
    *(us8*)&Ks[kr][kc + 8] = kst[1];                                   \
    *(us8*)&Ks[64 + kr][kc] = kst[2];                                  \
    *(us8*)&Ks[64 + kr][kc + 8] = kst[3];                              \
    _Pragma("unroll") for (int j = 0; j < 4; ++j)                      \
        *(us8*)&Vts[vd][vm + j * 8] = vst[j];                          \
  }

  LOADC(0);
  STOREC();
  if (NCH > 1) LOADC(1);
  __syncthreads();

  for (int c = 0; c < NCH; ++c) {
#pragma unroll
    for (int t = 0; t < 4; ++t) {
      // K fragments for this 32-key tile: A[row=m=t*32+l32][k=kk*16+hi*8+j]
      half8 kf[4];
#pragma unroll
      for (int kk = 0; kk < 4; ++kk)
        kf[kk] = *(const half8*)&Ks[t * 32 + l32][kk * 16 + hi * 8];
      // V^T fragments: A[row=d=dt*32+l32][k=m=mm*16+hi*8+j]
      half8 vf[2][2];
#pragma unroll
      for (int dt = 0; dt < 2; ++dt)
#pragma unroll
        for (int mm = 0; mm < 2; ++mm)
          vf[dt][mm] =
              *(const half8*)&Vts[dt * 32 + l32][t * 32 + mm * 16 + hi * 8];

#pragma unroll
      for (int qt = 0; qt < 2; ++qt) {
        floatx16 s;
#pragma unroll
        for (int r = 0; r < 16; ++r) s[r] = 0.f;
        __builtin_amdgcn_s_setprio(1);
#pragma unroll
        for (int kk = 0; kk < 4; ++kk)
          s = __builtin_amdgcn_mfma_f32_32x32x16_f16(kf[kk], qf[qt][kk], s,
                                                     0, 0, 0);
        __builtin_amdgcn_s_setprio(0);
        // lane (hi,l32) holds P[m=(r&3)+8*(r>>2)+4*hi][q=l32], r=0..15
        float e[16];
#pragma unroll
        for (int r = 0; r < 16; ++r) e[r] = EXP2F(s[r]);
        sl[qt] += ((((e[0] + e[1]) + (e[2] + e[3])) +
                    ((e[4] + e[5]) + (e[6] + e[7]))) +
                   (((e[8] + e[9]) + (e[10] + e[11])) +
                    ((e[12] + e[13]) + (e[14] + e[15]))));
        // pack pairs (m, m+1) and build PV B-frags via lane<->lane+32 swap
        union { pkhalf2 h; unsigned u; } p01, p23, p45, p67, p89, pab, pcd, pef;
        p01.h = __builtin_amdgcn_cvt_pkrtz(e[0], e[1]);
        p23.h = __builtin_amdgcn_cvt_pkrtz(e[2], e[3]);
        p45.h = __builtin_amdgcn_cvt_pkrtz(e[4], e[5]);
        p67.h = __builtin_amdgcn_cvt_pkrtz(e[6], e[7]);
        p89.h = __builtin_amdgcn_cvt_pkrtz(e[8], e[9]);
        pab.h = __builtin_amdgcn_cvt_pkrtz(e[10], e[11]);
        pcd.h = __builtin_amdgcn_cvt_pkrtz(e[12], e[13]);
        pef.h = __builtin_amdgcn_cvt_pkrtz(e[14], e[15]);
        unsigned a0 = p01.u, a1 = p23.u, a2 = p45.u, a3 = p67.u;
        unsigned b0 = p89.u, b1 = pab.u, b2 = pcd.u, b3 = pef.u;
        // after swap: vdst = [own.lo | other.lo], vsrc = [other.hi | own.hi]
        asm("v_permlane32_swap_b32 %0, %1" : "+v"(a0), "+v"(a2));
        asm("v_permlane32_swap_b32 %0, %1" : "+v"(a1), "+v"(a3));
        asm("v_permlane32_swap_b32 %0, %1" : "+v"(b0), "+v"(b2));
        asm("v_permlane32_swap_b32 %0, %1" : "+v"(b1), "+v"(b3));
        union { half8 h; unsigned u[4]; } pa0, pa1;
        pa0.u[0] = a0; pa0.u[1] = a1; pa0.u[2] = a2; pa0.u[3] = a3;
        pa1.u[0] = b0; pa1.u[1] = b1; pa1.u[2] = b2; pa1.u[3] = b3;
        __builtin_amdgcn_s_setprio(1);
#pragma unroll
        for (int dt = 0; dt < 2; ++dt) {
          zacc[qt][dt] = __builtin_amdgcn_mfma_f32_32x32x16_f16(
              vf[dt][0], pa0.h, zacc[qt][dt], 0, 0, 0);
          zacc[qt][dt] = __builtin_amdgcn_mfma_f32_32x32x16_f16(
              vf[dt][1], pa1.h, zacc[qt][dt], 0, 0, 0);
        }
        __builtin_amdgcn_s_setprio(0);
      }
    }
    __syncthreads();  // this chunk's LDS reads complete
    if (c + 1 < NCH) {
      STOREC();               // chunk c+1, regs loaded one full chunk ago
      if (c + 2 < NCH) LOADC(c + 2);
      __syncthreads();        // staging visible before next compute
    }
  }

  // ---- partial epilogue: Z^T partials as f16; rowsum via one shfl_xor ----
  // Per (dt, pair-of-d8-blocks): cvt_pkrtz 8 accs -> 4 words, 2
  // permlane32_swaps so lo-lane holds d 0..7 and hi-lane d 8..15 contiguous;
  // one aligned us8 store per lane => 32 contiguous B per row per instr.
#pragma unroll
  for (int qt = 0; qt < 2; ++qt) {
    float s = sl[qt];
    s += __shfl_xor(s, 32, 64);
    const int n = n0 + w * 64 + qt * 32 + l32;
    ushort_t* dst = Zp + z * 2097152 + n * EDIM + h * 64;
#pragma unroll
    for (int dt = 0; dt < 2; ++dt)
#pragma unroll
      for (int pr = 0; pr < 2; ++pr) {
        union { pkhalf2 h; unsigned u; } x0, x1, y0, y1;
        x0.h = __builtin_amdgcn_cvt_pkrtz(zacc[qt][dt][pr * 8 + 0],
                                          zacc[qt][dt][pr * 8 + 1]);
        x1.h = __builtin_amdgcn_cvt_pkrtz(zacc[qt][dt][pr * 8 + 2],
                                          zacc[qt][dt][pr * 8 + 3]);
        y0.h = __builtin_amdgcn_cvt_pkrtz(zacc[qt][dt][pr * 8 + 4],
                                          zacc[qt][dt][pr * 8 + 5]);
        y1.h = __builtin_amdgcn_cvt_pkrtz(zacc[qt][dt][pr * 8 + 6],
                                          zacc[qt][dt][pr * 8 + 7]);
        unsigned a0 = x0.u, a1 = x1.u, b0 = y0.u, b1 = y1.u;
        // lo lane: [d0,1 d2,3 | d4,5 d6,7]; hi lane: [d8,9 ... d14,15]
        asm("v_permlane32_swap_b32 %0, %1" : "+v"(a0), "+v"(b0));
        asm("v_permlane32_swap_b32 %0, %1" : "+v"(a1), "+v"(b1));
        union { us8 v; unsigned u[4]; } o;
        o.u[0] = a0; o.u[1] = a1; o.u[2] = b0; o.u[3] = b1;
        *(us8*)(dst + dt * 32 + pr * 16 + hi * 8) = o.v;
      }
    if (hi == 0) Lp[z * 32768 + h * 4096 + n] = s;
  }
}

extern "C" void kernel_launch(void* const* d_in, const int* in_sizes, int n_in,
                              void* d_out, int out_size, void* d_ws,
                              size_t ws_size, hipStream_t stream) {
  const float* inp = (const float*)d_in[0];
  const float* WKw = (const float*)d_in[1];
  const float* WKb = (const float*)d_in[2];
  const float* WQw = (const float*)d_in[3];
  const float* WQb = (const float*)d_in[4];
  const float* WVw = (const float*)d_in[5];
  const float* WVb = (const float*)d_in[6];
  const float* WZw = (const float*)d_in[7];
  const float* WZb = (const float*)d_in[8];

  char* ws = (char*)d_ws;
  const size_t MB = 1 << 20;
  ushort_t* Xf = (ushort_t*)(ws);                        // 4MB; Zf after attn
  ushort_t* WQf = (ushort_t*)(ws + 4 * MB);              // 512KB each
  ushort_t* WKf = (ushort_t*)(ws + 4 * MB + 512 * 1024);
  ushort_t* WVf = (ushort_t*)(ws + 5 * MB);
  ushort_t* WZf = (ushort_t*)(ws + 5 * MB + 512 * 1024);
  ushort_t* Qb = (ushort_t*)(ws + 6 * MB);    // 4MB f16 (E,N) scrambled, *C2
  ushort_t* Kb = (ushort_t*)(ws + 10 * MB);   // 4MB f16 (N,E)
  ushort_t* Vtb = (ushort_t*)(ws + 14 * MB);  // 4MB f16 [h][d][m]
  ushort_t* Zp = (ushort_t*)(ws + 18 * MB);   // SPL*4MB: [SPL][4096][512] f16
  // Lp sits after Zp: [SPL][8][4096] f32

  cast_all<<<3072, 256, 0, stream>>>(inp, Xf, WKw, WQw, WVw, WZw, WKf, WQf,
                                     WVf, WZf);

  gemm_qkv<<<dim3(NSEQ / 128, EDIM / 64, 3), 256, 0, stream>>>(
      WQf, WQb, WKf, WKb, WVf, WVb, Xf, Qb, Kb, Vtb);

  if (ws_size >= 52 * MB) {  // split-K 8: 18 + 32 (Zp) + 1 (Lp) = 51MB
    float* Lp = (float*)(ws + 18 * MB + 8 * 4 * MB);
    attn_mfma<8><<<dim3(NSEQ / 256, NHEAD, 8), 256, 0, stream>>>(Qb, Kb, Vtb,
                                                                 Zp, Lp);
    combine<8><<<1024, 256, 0, stream>>>(Zp, Lp, Xf);  // Xf reused as Zf
  } else {                   // fallback: split-K 4 (35MB)
    float* Lp = (float*)(ws + 18 * MB + 4 * 4 * MB);
    attn_mfma<4><<<dim3(NSEQ / 256, NHEAD, 4), 256, 0, stream>>>(Qb, Kb, Vtb,
                                                                 Zp, Lp);
    combine<4><<<1024, 256, 0, stream>>>(Zp, Lp, Xf);  // Xf reused as Zf
  }

  gemm_out<<<dim3(NSEQ / 64, EDIM / 64), 256, 0, stream>>>(WZf, Xf, WZb,
                                                           (float*)d_out);
}

// Round 5
// 151.442 us; speedup vs baseline: 4.4106x; 4.4106x over previous
//
#include <hip/hip_runtime.h>
#include <math.h>

#define NSEQ 4096
#define EDIM 512
#define NHEAD 8
#define DHEAD 64

// LESSON (R4, R8): direct-from-global MFMA fragment loads regress vs
// LDS-staged ds_read_b128 fragments, even when perfectly coalesced/tiled.
// LESSON (R10/R14): bigger K-chunks regress (LDS size/occupancy beats
// barrier-amortization on this chip).
// LESSON (R11/R12): wider per-wave q-tiles cut fragment re-reads 2x.
// LESSON (R13): folding fp32 casts into GEMM staging regresses ~18us.
// LESSON (R15/R16): traffic changes pay exactly their traffic cost.
// R17: rowsum via VALU adds + shfl_xor instead of ones-MFMA.
// R18: 32x32x16 MFMA + in-register P (cvt_pkrtz + v_permlane32_swap_b32).
// R19: us8-granular Zp stores (no TCC partial-write RMW): attn 44.4us.
// R20: intra-wave dbuf/prefetch: 44.4->42.7us only. Model: MFMA 32% + VALU
// ~28% + LDS ~30% = fully serialized chain; TLP-starved at 2 waves/SIMD.
// R21 FAILED: __launch_bounds__(256,4) forced 64 arch-VGPR -> inner-loop
// scratch spills (FETCH 779MB, attn 560us). LESSON: never tighten
// launch_bounds to chase occupancy; R19's 100 VGPR + 35840B LDS already
// PERMIT 4 blocks/CU -- only the 512-block grid capped residency at 2.
// R22: split-K 8 => 1024 blocks = exactly 4 blocks/CU, R19 loop body
// (single buffer, no reg-carried prefetch, VGPR ~100), launch_bounds(256,2)
// untouched. TLP covers the vmcnt/barrier stalls. T5 setprio kept (inter-
// block phase diversity now exists). Cost: +32MB Zp/combine traffic.

typedef unsigned short ushort_t;
typedef __attribute__((ext_vector_type(8))) _Float16 half8;    // 8 f16 (4 VGPRs)
typedef __attribute__((ext_vector_type(2))) __fp16 pkhalf2;    // cvt_pkrtz out
typedef __attribute__((ext_vector_type(4))) float floatx4;     // MFMA C/D 16x16
typedef __attribute__((ext_vector_type(16))) float floatx16;   // MFMA C/D 32x32
typedef __attribute__((ext_vector_type(8))) ushort_t us8;
typedef __attribute__((ext_vector_type(4))) ushort_t us4;

#define C2SCALE 0.02254211f  // log2(e)/64, folded into Q at projection

__device__ __forceinline__ ushort_t f2h(float x) {  // RNE float->f16
  union { _Float16 h; ushort_t u; } v;
  v.h = (_Float16)x;
  return v.u;
}

#if __has_builtin(__builtin_amdgcn_exp2f)
#define EXP2F(x) __builtin_amdgcn_exp2f(x)
#else
#define EXP2F(x) exp2f(x)
#endif

// ---------------------------------------------------------------------------
// fused fp32 -> f16 cast for inp (2048 blocks) + 4 weight mats (1024 blocks)
// ---------------------------------------------------------------------------
__global__ __launch_bounds__(256) void cast_all(
    const float* __restrict__ inp, ushort_t* __restrict__ Xf,
    const float* __restrict__ w0, const float* __restrict__ w1,
    const float* __restrict__ w2, const float* __restrict__ w3,
    ushort_t* __restrict__ d0, ushort_t* __restrict__ d1,
    ushort_t* __restrict__ d2, ushort_t* __restrict__ d3) {
  const int bid = blockIdx.x;
  const float* s;
  ushort_t* d;
  int blk;
  if (bid < 2048) {
    s = inp; d = Xf; blk = bid;
  } else {
    const int seg = (bid - 2048) >> 8;
    blk = (bid - 2048) & 255;
    switch (seg) {
      case 0: s = w0; d = d0; break;
      case 1: s = w1; d = d1; break;
      case 2: s = w2; d = d2; break;
      default: s = w3; d = d3; break;
    }
  }
  const int i = (blk * 256 + threadIdx.x) * 4;
  const float4 v = *(const float4*)(s + i);
  us4 o;
  o[0] = f2h(v.x); o[1] = f2h(v.y); o[2] = f2h(v.z); o[3] = f2h(v.w);
  *(us4*)(d + i) = o;
}

// ---------------------------------------------------------------------------
// Fused QKV single-plane f16 MFMA NT GEMM, LDS-staged, BK=64, 3 blocks/CU.
// 64o x 128n tile.
// z=0: Q -> f16 (E,N) scaled by C2SCALE.   z=1: K -> f16 (N,E).
// z=2: V -> f16 Vt[h][d][m] DIRECTLY (strided n-tile; see R15).
// ---------------------------------------------------------------------------
__global__ __launch_bounds__(256, 3) void gemm_qkv(
    const ushort_t* __restrict__ WQf, const float* __restrict__ WQb,
    const ushort_t* __restrict__ WKf, const float* __restrict__ WKb,
    const ushort_t* __restrict__ WVf, const float* __restrict__ WVb,
    const ushort_t* __restrict__ Xf, ushort_t* __restrict__ Qb,
    ushort_t* __restrict__ Kb, ushort_t* __restrict__ Vt) {
  __shared__ __align__(16) char smem[27648];
  ushort_t(*Ws)[72] = (ushort_t(*)[72])smem;           // [64][72]
  ushort_t(*Xs)[72] = (ushort_t(*)[72])(smem + 9216);  // [128][72]

  const int tid = threadIdx.x;
  const int w = tid >> 6, lane = tid & 63, quad = lane >> 4, l16 = lane & 15;
  const int o0 = blockIdx.y * 64, n0 = blockIdx.x * 128, z = blockIdx.z;
  const int wr = tid >> 2, wseg = (tid & 3) * 16;  // W stage: 64 rows x 16 k
  const int xr = tid >> 1, xseg = (tid & 1) * 32;  // X stage: 128 rows x 32 k
  const int xrow = (z == 2)
                       ? ((xr >> 1) * 64 + blockIdx.x * 2 + (xr & 1))
                       : (n0 + xr);

  const ushort_t* Wf = (z == 0) ? WQf : (z == 1) ? WKf : WVf;
  const float* bias = (z == 0) ? WQb : (z == 1) ? WKb : WVb;

  floatx4 acc[4][2];
#pragma unroll
  for (int ot = 0; ot < 4; ++ot)
#pragma unroll
    for (int nt = 0; nt < 2; ++nt) {
      acc[ot][nt][0] = 0.f; acc[ot][nt][1] = 0.f;
      acc[ot][nt][2] = 0.f; acc[ot][nt][3] = 0.f;
    }

  for (int k0 = 0; k0 < EDIM; k0 += 64) {
    const us8 w0 = *(const us8*)(Wf + (o0 + wr) * 512 + k0 + wseg);
    const us8 w1 = *(const us8*)(Wf + (o0 + wr) * 512 + k0 + wseg + 8);
    us8 xv[4];
#pragma unroll
    for (int j = 0; j < 4; ++j)
      xv[j] = *(const us8*)(Xf + xrow * 512 + k0 + xseg + j * 8);
    __syncthreads();  // previous iteration's LDS reads complete
    *(us8*)&Ws[wr][wseg] = w0;
    *(us8*)&Ws[wr][wseg + 8] = w1;
#pragma unroll
    for (int j = 0; j < 4; ++j) *(us8*)&Xs[xr][xseg + j * 8] = xv[j];
    __syncthreads();

    half8 a[2][4], b[2][2];
#pragma unroll
    for (int kh = 0; kh < 2; ++kh) {
#pragma unroll
      for (int ot = 0; ot < 4; ++ot)
        a[kh][ot] = *(const half8*)&Ws[ot * 16 + l16][kh * 32 + quad * 8];
#pragma unroll
      for (int nt = 0; nt < 2; ++nt)
        b[kh][nt] =
            *(const half8*)&Xs[w * 32 + nt * 16 + l16][kh * 32 + quad * 8];
    }
#pragma unroll
    for (int kh = 0; kh < 2; ++kh)
#pragma unroll
      for (int ot = 0; ot < 4; ++ot)
#pragma unroll
        for (int nt = 0; nt < 2; ++nt)
          acc[ot][nt] = __builtin_amdgcn_mfma_f32_16x16x32_f16(
              a[kh][ot], b[kh][nt], acc[ot][nt], 0, 0, 0);
  }

  __syncthreads();  // staging reads done; smem reused for epilogue
  float bo[4][4];
#pragma unroll
  for (int ot = 0; ot < 4; ++ot)
#pragma unroll
    for (int r = 0; r < 4; ++r)
      bo[ot][r] = bias[o0 + ot * 16 + quad * 4 + r];

  if (z == 0) {  // Q: f16 (E,N), scaled
    ushort_t(*Cs)[136] = (ushort_t(*)[136])smem;
#pragma unroll
    for (int ot = 0; ot < 4; ++ot)
#pragma unroll
      for (int nt = 0; nt < 2; ++nt)
#pragma unroll
        for (int r = 0; r < 4; ++r)
          Cs[ot * 16 + quad * 4 + r][w * 32 + nt * 16 + l16] =
              f2h((acc[ot][nt][r] + bo[ot][r]) * C2SCALE);
    __syncthreads();
    const int row = tid >> 2, seg = (tid & 3) * 32;
#pragma unroll
    for (int j = 0; j < 4; ++j)
      *(us8*)(Qb + (o0 + row) * 4096 + n0 + seg + j * 8) =
          *(const us8*)&Cs[row][seg + j * 8];
  } else if (z == 1) {  // K: f16 (N,E)
    ushort_t(*Cs)[72] = (ushort_t(*)[72])smem;
#pragma unroll
    for (int ot = 0; ot < 4; ++ot)
#pragma unroll
      for (int nt = 0; nt < 2; ++nt)
#pragma unroll
        for (int r = 0; r < 4; ++r)
          Cs[w * 32 + nt * 16 + l16][ot * 16 + quad * 4 + r] =
              f2h(acc[ot][nt][r] + bo[ot][r]);
    __syncthreads();
    const int row = tid >> 1, seg = (tid & 1) * 32;
#pragma unroll
    for (int j = 0; j < 4; ++j)
      *(us8*)(Kb + (n0 + row) * 512 + o0 + seg + j * 8) =
          *(const us8*)&Cs[row][seg + j * 8];
  } else {  // V: emit Vt[h][d][m] directly
    ushort_t(*Cs)[72] = (ushort_t(*)[72])smem;  // [local n][o-local]
#pragma unroll
    for (int ot = 0; ot < 4; ++ot)
#pragma unroll
      for (int nt = 0; nt < 2; ++nt)
#pragma unroll
        for (int r = 0; r < 4; ++r)
          Cs[w * 32 + nt * 16 + l16][ot * 16 + quad * 4 + r] =
              f2h(acc[ot][nt][r] + bo[ot][r]);
    __syncthreads();
    const int h = blockIdx.y;
    const int d0 = blockIdx.x * 2;
#pragma unroll
    for (int t = 0; t < 4; ++t) {
      const int c = tid + t * 256;   // 0..1023 us8-chunks
      const int oo = c >> 4;         // 0..63
      const int dd = (c >> 3) & 1;
      const int g = c & 7;           // nh-group of 8
      us8 v;
#pragma unroll
      for (int j = 0; j < 8; ++j) v[j] = Cs[(g * 8 + j) * 2 + dd][oo];
      *(us8*)(Vt + h * 262144 + (d0 + dd) * 4096 + oo * 64 + g * 8) = v;
    }
  }
}

// ---------------------------------------------------------------------------
// combine: Zf[n][e] = (sum_z Zp[z][n][e]) / (sum_z Lp[z][h][n]), f16 out.
// ---------------------------------------------------------------------------
template <int SPL>
__global__ __launch_bounds__(256) void combine(const ushort_t* __restrict__ Zp,
                                               const float* __restrict__ Lp,
                                               ushort_t* __restrict__ Zf) {
  const int base = (blockIdx.x * 256 + threadIdx.x) * 8;
  const int n = base >> 9, e = base & 511, h = e >> 6;
  float lsum = 0.f;
  float va[8];
#pragma unroll
  for (int j = 0; j < 8; ++j) va[j] = 0.f;
#pragma unroll
  for (int zz = 0; zz < SPL; ++zz) {
    const half8 v = *(const half8*)(Zp + zz * 2097152 + base);
#pragma unroll
    for (int j = 0; j < 8; ++j) va[j] += (float)v[j];
    lsum += Lp[zz * 32768 + h * 4096 + n];
  }
  const float inv = 1.0f / lsum;
  us8 o;
#pragma unroll
  for (int j = 0; j < 8; ++j) o[j] = f2h(va[j] * inv);
  *(us8*)(Zf + base) = o;
}

// ---------------------------------------------------------------------------
// Output projection: f16 W and Zf from LDS, fp32 (N,E) out. BK=64,
// 64o x 64n tile, 512 blocks.
// ---------------------------------------------------------------------------
__global__ __launch_bounds__(256, 2) void gemm_out(
    const ushort_t* __restrict__ Wf, const ushort_t* __restrict__ Zf,
    const float* __restrict__ bias, float* __restrict__ C) {
  __shared__ __align__(16) char smem[18432];
  ushort_t(*Ws)[72] = (ushort_t(*)[72])smem;           // [64][72]
  ushort_t(*Xs)[72] = (ushort_t(*)[72])(smem + 9216);  // [64][72]

  const int tid = threadIdx.x;
  const int w = tid >> 6, lane = tid & 63, quad = lane >> 4, l16 = lane & 15;
  const int o0 = blockIdx.y * 64, n0 = blockIdx.x * 64;
  const int lr = tid >> 2, lseg = (tid & 3) * 16;

  floatx4 acc[4];
#pragma unroll
  for (int ot = 0; ot < 4; ++ot) {
    acc[ot][0] = 0.f; acc[ot][1] = 0.f; acc[ot][2] = 0.f; acc[ot][3] = 0.f;
  }

  for (int k0 = 0; k0 < EDIM; k0 += 64) {
    const us8 w0 = *(const us8*)(Wf + (o0 + lr) * 512 + k0 + lseg);
    const us8 w1 = *(const us8*)(Wf + (o0 + lr) * 512 + k0 + lseg + 8);
    const us8 x0 = *(const us8*)(Zf + (n0 + lr) * 512 + k0 + lseg);
    const us8 x1 = *(const us8*)(Zf + (n0 + lr) * 512 + k0 + lseg + 8);
    __syncthreads();
    *(us8*)&Ws[lr][lseg] = w0;
    *(us8*)&Ws[lr][lseg + 8] = w1;
    *(us8*)&Xs[lr][lseg] = x0;
    *(us8*)&Xs[lr][lseg + 8] = x1;
    __syncthreads();

    half8 a[2][4], b[2];
#pragma unroll
    for (int kh = 0; kh < 2; ++kh) {
#pragma unroll
      for (int ot = 0; ot < 4; ++ot)
        a[kh][ot] = *(const half8*)&Ws[ot * 16 + l16][kh * 32 + quad * 8];
      b[kh] = *(const half8*)&Xs[w * 16 + l16][kh * 32 + quad * 8];
    }
#pragma unroll
    for (int kh = 0; kh < 2; ++kh)
#pragma unroll
      for (int ot = 0; ot < 4; ++ot)
        acc[ot] = __builtin_amdgcn_mfma_f32_16x16x32_f16(a[kh][ot], b[kh],
                                                         acc[ot], 0, 0, 0);
  }

  __syncthreads();
  float(*Cs)[68] = (float(*)[68])smem;
#pragma unroll
  for (int ot = 0; ot < 4; ++ot) {
    floatx4 v = acc[ot];
#pragma unroll
    for (int r = 0; r < 4; ++r) v[r] += bias[o0 + ot * 16 + quad * 4 + r];
    *(floatx4*)&Cs[w * 16 + l16][ot * 16 + quad * 4] = v;
  }
  __syncthreads();
  const int row = tid >> 2, seg = (tid & 3) * 16;
#pragma unroll
  for (int j = 0; j < 4; ++j)
    *(float4*)(C + (n0 + row) * 512 + o0 + seg + j * 4) =
        *(const float4*)&Cs[row][seg + j * 4];
}

// ---------------------------------------------------------------------------
// Flash attention, R22: 32x32x16 f16 MFMA, transposed-score, single-buffer
// LDS K/V (R19 loop: load -> barrier -> store -> barrier -> compute),
// in-register P (cvt_pkrtz + v_permlane32_swap_b32), us8-granular Z^T
// partials, split-K SPL=8 -> 1024 blocks = exactly 4 blocks/CU by grid;
// VGPR ~100 and LDS 35840 both permit 4, launch_bounds left at (256,2).
//   QK:  s = mfma32(kf, qf)    D[col=q=l32][row=m=(r&3)+8*(r>>2)+4*hi]
//   PV:  z = mfma32(vf, pa)    D[col=q=l32][row=d-local]
// ---------------------------------------------------------------------------
template <int SPL>
__global__ __launch_bounds__(256, 2) void attn_mfma(
    const ushort_t* __restrict__ Qb, const ushort_t* __restrict__ Kb,
    const ushort_t* __restrict__ Vt, ushort_t* __restrict__ Zp,
    float* __restrict__ Lp) {
  __shared__ __align__(16) ushort_t Ks[128][72];    // K chunk [m][d]
  __shared__ __align__(16) ushort_t Vts[64][136];   // V^T chunk [d][m]

  const int tid = threadIdx.x;
  const int w = tid >> 6;
  const int lane = tid & 63;
  const int hi = lane >> 5;
  const int l32 = lane & 31;
  const int h = blockIdx.y;
  const int n0 = blockIdx.x * 256;
  const int z = blockIdx.z;
  const int mbase = z * (NSEQ / SPL);

  // Q fragments: B-operand, B[col=q=l32][k=d=kk*16+hi*8+j]
  half8 qf[2][4];
#pragma unroll
  for (int qt = 0; qt < 2; ++qt) {
    const ushort_t* qsrc =
        Qb + h * 262144 + (n0 + w * 64 + qt * 32 + l32) * 64 + hi * 8;
#pragma unroll
    for (int kk = 0; kk < 4; ++kk)
      qf[qt][kk] = *(const half8*)(qsrc + kk * 16);
  }

  floatx16 zacc[2][2];
  float sl[2] = {0.f, 0.f};
#pragma unroll
  for (int qt = 0; qt < 2; ++qt)
#pragma unroll
    for (int dt = 0; dt < 2; ++dt)
#pragma unroll
      for (int r = 0; r < 16; ++r) zacc[qt][dt][r] = 0.f;

  const int kr = tid >> 2;
  const int kc = (tid & 3) << 4;
  const int vd = tid >> 2;
  const int vm = (tid & 3) << 5;

  for (int m0 = 0; m0 < NSEQ / SPL; m0 += 128) {
    const ushort_t* ksrc = Kb + h * 262144 + (mbase + m0) * 64;
    const ushort_t* vsrc = Vt + h * 262144 + vd * 4096 + mbase + m0 + vm;
    us8 kst[4], vst[4];
    kst[0] = *(const us8*)(ksrc + kr * 64 + kc);
    kst[1] = *(const us8*)(ksrc + kr * 64 + kc + 8);
    kst[2] = *(const us8*)(ksrc + (64 + kr) * 64 + kc);
    kst[3] = *(const us8*)(ksrc + (64 + kr) * 64 + kc + 8);
#pragma unroll
    for (int j = 0; j < 4; ++j) vst[j] = *(const us8*)(vsrc + j * 8);

    __syncthreads();  // previous chunk's LDS reads complete
    *(us8*)&Ks[kr][kc] = kst[0];
    *(us8*)&Ks[kr][kc + 8] = kst[1];
    *(us8*)&Ks[64 + kr][kc] = kst[2];
    *(us8*)&Ks[64 + kr][kc + 8] = kst[3];
#pragma unroll
    for (int j = 0; j < 4; ++j) *(us8*)&Vts[vd][vm + j * 8] = vst[j];
    __syncthreads();

#pragma unroll
    for (int t = 0; t < 4; ++t) {
      // K fragments for this 32-key tile: A[row=m=t*32+l32][k=kk*16+hi*8+j]
      half8 kf[4];
#pragma unroll
      for (int kk = 0; kk < 4; ++kk)
        kf[kk] = *(const half8*)&Ks[t * 32 + l32][kk * 16 + hi * 8];
      // V^T fragments: A[row=d=dt*32+l32][k=m=mm*16+hi*8+j]
      half8 vf[2][2];
#pragma unroll
      for (int dt = 0; dt < 2; ++dt)
#pragma unroll
        for (int mm = 0; mm < 2; ++mm)
          vf[dt][mm] =
              *(const half8*)&Vts[dt * 32 + l32][t * 32 + mm * 16 + hi * 8];

#pragma unroll
      for (int qt = 0; qt < 2; ++qt) {
        floatx16 s;
#pragma unroll
        for (int r = 0; r < 16; ++r) s[r] = 0.f;
        __builtin_amdgcn_s_setprio(1);
#pragma unroll
        for (int kk = 0; kk < 4; ++kk)
          s = __builtin_amdgcn_mfma_f32_32x32x16_f16(kf[kk], qf[qt][kk], s,
                                                     0, 0, 0);
        __builtin_amdgcn_s_setprio(0);
        // lane (hi,l32) holds P[m=(r&3)+8*(r>>2)+4*hi][q=l32], r=0..15
        float e[16];
#pragma unroll
        for (int r = 0; r < 16; ++r) e[r] = EXP2F(s[r]);
        sl[qt] += ((((e[0] + e[1]) + (e[2] + e[3])) +
                    ((e[4] + e[5]) + (e[6] + e[7]))) +
                   (((e[8] + e[9]) + (e[10] + e[11])) +
                    ((e[12] + e[13]) + (e[14] + e[15]))));
        // pack pairs (m, m+1) and build PV B-frags via lane<->lane+32 swap
        union { pkhalf2 h; unsigned u; } p01, p23, p45, p67, p89, pab, pcd, pef;
        p01.h = __builtin_amdgcn_cvt_pkrtz(e[0], e[1]);
        p23.h = __builtin_amdgcn_cvt_pkrtz(e[2], e[3]);
        p45.h = __builtin_amdgcn_cvt_pkrtz(e[4], e[5]);
        p67.h = __builtin_amdgcn_cvt_pkrtz(e[6], e[7]);
        p89.h = __builtin_amdgcn_cvt_pkrtz(e[8], e[9]);
        pab.h = __builtin_amdgcn_cvt_pkrtz(e[10], e[11]);
        pcd.h = __builtin_amdgcn_cvt_pkrtz(e[12], e[13]);
        pef.h = __builtin_amdgcn_cvt_pkrtz(e[14], e[15]);
        unsigned a0 = p01.u, a1 = p23.u, a2 = p45.u, a3 = p67.u;
        unsigned b0 = p89.u, b1 = pab.u, b2 = pcd.u, b3 = pef.u;
        // after swap: vdst = [own.lo | other.lo], vsrc = [other.hi | own.hi]
        asm("v_permlane32_swap_b32 %0, %1" : "+v"(a0), "+v"(a2));
        asm("v_permlane32_swap_b32 %0, %1" : "+v"(a1), "+v"(a3));
        asm("v_permlane32_swap_b32 %0, %1" : "+v"(b0), "+v"(b2));
        asm("v_permlane32_swap_b32 %0, %1" : "+v"(b1), "+v"(b3));
        union { half8 h; unsigned u[4]; } pa0, pa1;
        pa0.u[0] = a0; pa0.u[1] = a1; pa0.u[2] = a2; pa0.u[3] = a3;
        pa1.u[0] = b0; pa1.u[1] = b1; pa1.u[2] = b2; pa1.u[3] = b3;
        __builtin_amdgcn_s_setprio(1);
#pragma unroll
        for (int dt = 0; dt < 2; ++dt) {
          zacc[qt][dt] = __builtin_amdgcn_mfma_f32_32x32x16_f16(
              vf[dt][0], pa0.h, zacc[qt][dt], 0, 0, 0);
          zacc[qt][dt] = __builtin_amdgcn_mfma_f32_32x32x16_f16(
              vf[dt][1], pa1.h, zacc[qt][dt], 0, 0, 0);
        }
        __builtin_amdgcn_s_setprio(0);
      }
    }
  }

  // ---- partial epilogue: Z^T partials as f16; rowsum via one shfl_xor ----
  // Per (dt, pair-of-d8-blocks): cvt_pkrtz 8 accs -> 4 words, 2
  // permlane32_swaps so lo-lane holds d 0..7 and hi-lane d 8..15 contiguous;
  // one aligned us8 store per lane => 32 contiguous B per row per instr.
#pragma unroll
  for (int qt = 0; qt < 2; ++qt) {
    float s = sl[qt];
    s += __shfl_xor(s, 32, 64);
    const int n = n0 + w * 64 + qt * 32 + l32;
    ushort_t* dst = Zp + z * 2097152 + n * EDIM + h * 64;
#pragma unroll
    for (int dt = 0; dt < 2; ++dt)
#pragma unroll
      for (int pr = 0; pr < 2; ++pr) {
        union { pkhalf2 h; unsigned u; } x0, x1, y0, y1;
        x0.h = __builtin_amdgcn_cvt_pkrtz(zacc[qt][dt][pr * 8 + 0],
                                          zacc[qt][dt][pr * 8 + 1]);
        x1.h = __builtin_amdgcn_cvt_pkrtz(zacc[qt][dt][pr * 8 + 2],
                                          zacc[qt][dt][pr * 8 + 3]);
        y0.h = __builtin_amdgcn_cvt_pkrtz(zacc[qt][dt][pr * 8 + 4],
                                          zacc[qt][dt][pr * 8 + 5]);
        y1.h = __builtin_amdgcn_cvt_pkrtz(zacc[qt][dt][pr * 8 + 6],
                                          zacc[qt][dt][pr * 8 + 7]);
        unsigned a0 = x0.u, a1 = x1.u, b0 = y0.u, b1 = y1.u;
        // lo lane: [d0,1 d2,3 | d4,5 d6,7]; hi lane: [d8,9 ... d14,15]
        asm("v_permlane32_swap_b32 %0, %1" : "+v"(a0), "+v"(b0));
        asm("v_permlane32_swap_b32 %0, %1" : "+v"(a1), "+v"(b1));
        union { us8 v; unsigned u[4]; } o;
        o.u[0] = a0; o.u[1] = a1; o.u[2] = b0; o.u[3] = b1;
        *(us8*)(dst + dt * 32 + pr * 16 + hi * 8) = o.v;
      }
    if (hi == 0) Lp[z * 32768 + h * 4096 + n] = s;
  }
}

extern "C" void kernel_launch(void* const* d_in, const int* in_sizes, int n_in,
                              void* d_out, int out_size, void* d_ws,
                              size_t ws_size, hipStream_t stream) {
  const float* inp = (const float*)d_in[0];
  const float* WKw = (const float*)d_in[1];
  const float* WKb = (const float*)d_in[2];
  const float* WQw = (const float*)d_in[3];
  const float* WQb = (const float*)d_in[4];
  const float* WVw = (const float*)d_in[5];
  const float* WVb = (const float*)d_in[6];
  const float* WZw = (const float*)d_in[7];
  const float* WZb = (const float*)d_in[8];

  char* ws = (char*)d_ws;
  const size_t MB = 1 << 20;
  ushort_t* Xf = (ushort_t*)(ws);                        // 4MB; Zf after attn
  ushort_t* WQf = (ushort_t*)(ws + 4 * MB);              // 512KB each
  ushort_t* WKf = (ushort_t*)(ws + 4 * MB + 512 * 1024);
  ushort_t* WVf = (ushort_t*)(ws + 5 * MB);
  ushort_t* WZf = (ushort_t*)(ws + 5 * MB + 512 * 1024);
  ushort_t* Qb = (ushort_t*)(ws + 6 * MB);    // 4MB f16 (E,N) scrambled, *C2
  ushort_t* Kb = (ushort_t*)(ws + 10 * MB);   // 4MB f16 (N,E)
  ushort_t* Vtb = (ushort_t*)(ws + 14 * MB);  // 4MB f16 [h][d][m]
  ushort_t* Zp = (ushort_t*)(ws + 18 * MB);   // SPL*4MB: [SPL][4096][512] f16
  // Lp sits after Zp: [SPL][8][4096] f32

  cast_all<<<3072, 256, 0, stream>>>(inp, Xf, WKw, WQw, WVw, WZw, WKf, WQf,
                                     WVf, WZf);

  gemm_qkv<<<dim3(NSEQ / 128, EDIM / 64, 3), 256, 0, stream>>>(
      WQf, WQb, WKf, WKb, WVf, WVb, Xf, Qb, Kb, Vtb);

  if (ws_size >= 52 * MB) {  // split-K 8: 18 + 32 (Zp) + 1 (Lp) = 51MB
    float* Lp = (float*)(ws + 18 * MB + 8 * 4 * MB);
    attn_mfma<8><<<dim3(NSEQ / 256, NHEAD, 8), 256, 0, stream>>>(Qb, Kb, Vtb,
                                                                 Zp, Lp);
    combine<8><<<1024, 256, 0, stream>>>(Zp, Lp, Xf);  // Xf reused as Zf
  } else {                   // fallback: split-K 4 (35MB)
    float* Lp = (float*)(ws + 18 * MB + 4 * 4 * MB);
    attn_mfma<4><<<dim3(NSEQ / 256, NHEAD, 4), 256, 0, stream>>>(Qb, Kb, Vtb,
                                                                 Zp, Lp);
    combine<4><<<1024, 256, 0, stream>>>(Zp, Lp, Xf);  // Xf reused as Zf
  }

  gemm_out<<<dim3(NSEQ / 64, EDIM / 64), 256, 0, stream>>>(WZf, Xf, WZb,
                                                           (float*)d_out);
}

// Round 7
// 146.102 us; speedup vs baseline: 4.5718x; 1.0365x over previous
//
#include <hip/hip_runtime.h>
#include <math.h>

#define NSEQ 4096
#define EDIM 512
#define NHEAD 8
#define DHEAD 64

// LESSON (R4, R8): direct-from-global MFMA fragment loads regress vs
// LDS-staged ds_read_b128 fragments.
// LESSON (R10/R14): bigger K-chunks regress.
// LESSON (R13): folding fp32 casts into GEMM staging regresses ~18us.
// LESSON (R15/R16): traffic changes pay exactly their traffic cost.
// R17: rowsum via VALU adds + shfl_xor. attn 49.2us.
// R18: 32x32x16 MFMA + in-register P (cvt_pkrtz + v_permlane32_swap_b32).
// R19: us8-granular Zp stores (no TCC partial-write RMW): attn 44.4us.
// R20: dbuf + 1 barrier/chunk: 42.7us. Pipes: MFMA 32 / VALU 30 / LDS 30%
// -- serialized chain, no overlap.
// R21 FAILED: launch_bounds(256,4) -> 64 arch VGPR -> scratch spills.
// R22 FAILED: split-K 8: occupancy did NOT move (unified RF caps waves);
// TLP is capped -> intra-wave ILP is the only lever.
// R23 FAILED (NaN): big-bang macro pipeline (cross-t sA/sB ping-pong) --
// dataflow verified correct on paper; failure unexplained (suspect macro/
// inline-asm/codegen interaction). LESSON: move in minimal verifiable
// deltas from last-good.
// R24: exact R20 kernel + ONE change: inside each t, split the qt loop --
// issue both QK MFMA chains first, then both softmax+PV phases. QK(q1)'s
// MFMAs execute under softmax(q0)'s VALU; PV(q0) overlaps softmax(q1).
// s[2] statically indexed (fully unrolled).

typedef unsigned short ushort_t;
typedef __attribute__((ext_vector_type(8))) _Float16 half8;    // 8 f16 (4 VGPRs)
typedef __attribute__((ext_vector_type(2))) __fp16 pkhalf2;    // cvt_pkrtz out
typedef __attribute__((ext_vector_type(4))) float floatx4;     // MFMA C/D 16x16
typedef __attribute__((ext_vector_type(16))) float floatx16;   // MFMA C/D 32x32
typedef __attribute__((ext_vector_type(8))) ushort_t us8;
typedef __attribute__((ext_vector_type(4))) ushort_t us4;

#define C2SCALE 0.02254211f  // log2(e)/64, folded into Q at projection

__device__ __forceinline__ ushort_t f2h(float x) {  // RNE float->f16
  union { _Float16 h; ushort_t u; } v;
  v.h = (_Float16)x;
  return v.u;
}

#if __has_builtin(__builtin_amdgcn_exp2f)
#define EXP2F(x) __builtin_amdgcn_exp2f(x)
#else
#define EXP2F(x) exp2f(x)
#endif

// ---------------------------------------------------------------------------
// fused fp32 -> f16 cast for inp (2048 blocks) + 4 weight mats (1024 blocks)
// ---------------------------------------------------------------------------
__global__ __launch_bounds__(256) void cast_all(
    const float* __restrict__ inp, ushort_t* __restrict__ Xf,
    const float* __restrict__ w0, const float* __restrict__ w1,
    const float* __restrict__ w2, const float* __restrict__ w3,
    ushort_t* __restrict__ d0, ushort_t* __restrict__ d1,
    ushort_t* __restrict__ d2, ushort_t* __restrict__ d3) {
  const int bid = blockIdx.x;
  const float* s;
  ushort_t* d;
  int blk;
  if (bid < 2048) {
    s = inp; d = Xf; blk = bid;
  } else {
    const int seg = (bid - 2048) >> 8;
    blk = (bid - 2048) & 255;
    switch (seg) {
      case 0: s = w0; d = d0; break;
      case 1: s = w1; d = d1; break;
      case 2: s = w2; d = d2; break;
      default: s = w3; d = d3; break;
    }
  }
  const int i = (blk * 256 + threadIdx.x) * 4;
  const float4 v = *(const float4*)(s + i);
  us4 o;
  o[0] = f2h(v.x); o[1] = f2h(v.y); o[2] = f2h(v.z); o[3] = f2h(v.w);
  *(us4*)(d + i) = o;
}

// ---------------------------------------------------------------------------
// Fused QKV single-plane f16 MFMA NT GEMM, LDS-staged, BK=64, 3 blocks/CU.
// 64o x 128n tile.
// z=0: Q -> f16 (E,N) scaled by C2SCALE.   z=1: K -> f16 (N,E).
// z=2: V -> f16 Vt[h][d][m] DIRECTLY (strided n-tile; see R15).
// ---------------------------------------------------------------------------
__global__ __launch_bounds__(256, 3) void gemm_qkv(
    const ushort_t* __restrict__ WQf, const float* __restrict__ WQb,
    const ushort_t* __restrict__ WKf, const float* __restrict__ WKb,
    const ushort_t* __restrict__ WVf, const float* __restrict__ WVb,
    const ushort_t* __restrict__ Xf, ushort_t* __restrict__ Qb,
    ushort_t* __restrict__ Kb, ushort_t* __restrict__ Vt) {
  __shared__ __align__(16) char smem[27648];
  ushort_t(*Ws)[72] = (ushort_t(*)[72])smem;           // [64][72]
  ushort_t(*Xs)[72] = (ushort_t(*)[72])(smem + 9216);  // [128][72]

  const int tid = threadIdx.x;
  const int w = tid >> 6, lane = tid & 63, quad = lane >> 4, l16 = lane & 15;
  const int o0 = blockIdx.y * 64, n0 = blockIdx.x * 128, z = blockIdx.z;
  const int wr = tid >> 2, wseg = (tid & 3) * 16;  // W stage: 64 rows x 16 k
  const int xr = tid >> 1, xseg = (tid & 1) * 32;  // X stage: 128 rows x 32 k
  const int xrow = (z == 2)
                       ? ((xr >> 1) * 64 + blockIdx.x * 2 + (xr & 1))
                       : (n0 + xr);

  const ushort_t* Wf = (z == 0) ? WQf : (z == 1) ? WKf : WVf;
  const float* bias = (z == 0) ? WQb : (z == 1) ? WKb : WVb;

  floatx4 acc[4][2];
#pragma unroll
  for (int ot = 0; ot < 4; ++ot)
#pragma unroll
    for (int nt = 0; nt < 2; ++nt) {
      acc[ot][nt][0] = 0.f; acc[ot][nt][1] = 0.f;
      acc[ot][nt][2] = 0.f; acc[ot][nt][3] = 0.f;
    }

  for (int k0 = 0; k0 < EDIM; k0 += 64) {
    const us8 w0 = *(const us8*)(Wf + (o0 + wr) * 512 + k0 + wseg);
    const us8 w1 = *(const us8*)(Wf + (o0 + wr) * 512 + k0 + wseg + 8);
    us8 xv[4];
#pragma unroll
    for (int j = 0; j < 4; ++j)
      xv[j] = *(const us8*)(Xf + xrow * 512 + k0 + xseg + j * 8);
    __syncthreads();  // previous iteration's LDS reads complete
    *(us8*)&Ws[wr][wseg] = w0;
    *(us8*)&Ws[wr][wseg + 8] = w1;
#pragma unroll
    for (int j = 0; j < 4; ++j) *(us8*)&Xs[xr][xseg + j * 8] = xv[j];
    __syncthreads();

    half8 a[2][4], b[2][2];
#pragma unroll
    for (int kh = 0; kh < 2; ++kh) {
#pragma unroll
      for (int ot = 0; ot < 4; ++ot)
        a[kh][ot] = *(const half8*)&Ws[ot * 16 + l16][kh * 32 + quad * 8];
#pragma unroll
      for (int nt = 0; nt < 2; ++nt)
        b[kh][nt] =
            *(const half8*)&Xs[w * 32 + nt * 16 + l16][kh * 32 + quad * 8];
    }
#pragma unroll
    for (int kh = 0; kh < 2; ++kh)
#pragma unroll
      for (int ot = 0; ot < 4; ++ot)
#pragma unroll
        for (int nt = 0; nt < 2; ++nt)
          acc[ot][nt] = __builtin_amdgcn_mfma_f32_16x16x32_f16(
              a[kh][ot], b[kh][nt], acc[ot][nt], 0, 0, 0);
  }

  __syncthreads();  // staging reads done; smem reused for epilogue
  float bo[4][4];
#pragma unroll
  for (int ot = 0; ot < 4; ++ot)
#pragma unroll
    for (int r = 0; r < 4; ++r)
      bo[ot][r] = bias[o0 + ot * 16 + quad * 4 + r];

  if (z == 0) {  // Q: f16 (E,N), scaled
    ushort_t(*Cs)[136] = (ushort_t(*)[136])smem;
#pragma unroll
    for (int ot = 0; ot < 4; ++ot)
#pragma unroll
      for (int nt = 0; nt < 2; ++nt)
#pragma unroll
        for (int r = 0; r < 4; ++r)
          Cs[ot * 16 + quad * 4 + r][w * 32 + nt * 16 + l16] =
              f2h((acc[ot][nt][r] + bo[ot][r]) * C2SCALE);
    __syncthreads();
    const int row = tid >> 2, seg = (tid & 3) * 32;
#pragma unroll
    for (int j = 0; j < 4; ++j)
      *(us8*)(Qb + (o0 + row) * 4096 + n0 + seg + j * 8) =
          *(const us8*)&Cs[row][seg + j * 8];
  } else if (z == 1) {  // K: f16 (N,E)
    ushort_t(*Cs)[72] = (ushort_t(*)[72])smem;
#pragma unroll
    for (int ot = 0; ot < 4; ++ot)
#pragma unroll
      for (int nt = 0; nt < 2; ++nt)
#pragma unroll
        for (int r = 0; r < 4; ++r)
          Cs[w * 32 + nt * 16 + l16][ot * 16 + quad * 4 + r] =
              f2h(acc[ot][nt][r] + bo[ot][r]);
    __syncthreads();
    const int row = tid >> 1, seg = (tid & 1) * 32;
#pragma unroll
    for (int j = 0; j < 4; ++j)
      *(us8*)(Kb + (n0 + row) * 512 + o0 + seg + j * 8) =
          *(const us8*)&Cs[row][seg + j * 8];
  } else {  // V: emit Vt[h][d][m] directly
    ushort_t(*Cs)[72] = (ushort_t(*)[72])smem;  // [local n][o-local]
#pragma unroll
    for (int ot = 0; ot < 4; ++ot)
#pragma unroll
      for (int nt = 0; nt < 2; ++nt)
#pragma unroll
        for (int r = 0; r < 4; ++r)
          Cs[w * 32 + nt * 16 + l16][ot * 16 + quad * 4 + r] =
              f2h(acc[ot][nt][r] + bo[ot][r]);
    __syncthreads();
    const int h = blockIdx.y;
    const int d0 = blockIdx.x * 2;
#pragma unroll
    for (int t = 0; t < 4; ++t) {
      const int c = tid + t * 256;   // 0..1023 us8-chunks
      const int oo = c >> 4;         // 0..63
      const int dd = (c >> 3) & 1;
      const int g = c & 7;           // nh-group of 8
      us8 v;
#pragma unroll
      for (int j = 0; j < 8; ++j) v[j] = Cs[(g * 8 + j) * 2 + dd][oo];
      *(us8*)(Vt + h * 262144 + (d0 + dd) * 4096 + oo * 64 + g * 8) = v;
    }
  }
}

// ---------------------------------------------------------------------------
// combine: Zf[n][e] = (sum_z Zp[z][n][e]) / (sum_z Lp[z][h][n]), f16 out.
// Reads the 4 Zp planes ONCE (vs 8x when fused into gemm_out).
// ---------------------------------------------------------------------------
__global__ __launch_bounds__(256) void combine(const ushort_t* __restrict__ Zp,
                                               const float* __restrict__ Lp,
                                               ushort_t* __restrict__ Zf) {
  const int base = (blockIdx.x * 256 + threadIdx.x) * 8;
  const int n = base >> 9, e = base & 511, h = e >> 6;
  float lsum = 0.f;
  float va[8];
#pragma unroll
  for (int j = 0; j < 8; ++j) va[j] = 0.f;
#pragma unroll
  for (int zz = 0; zz < 4; ++zz) {
    const half8 v = *(const half8*)(Zp + zz * 2097152 + base);
#pragma unroll
    for (int j = 0; j < 8; ++j) va[j] += (float)v[j];
    lsum += Lp[zz * 32768 + h * 4096 + n];
  }
  const float inv = 1.0f / lsum;
  us8 o;
#pragma unroll
  for (int j = 0; j < 8; ++j) o[j] = f2h(va[j] * inv);
  *(us8*)(Zf + base) = o;
}

// ---------------------------------------------------------------------------
// Output projection: f16 W and Zf from LDS, fp32 (N,E) out. BK=64,
// 64o x 64n tile, 512 blocks.
// ---------------------------------------------------------------------------
__global__ __launch_bounds__(256, 2) void gemm_out(
    const ushort_t* __restrict__ Wf, const ushort_t* __restrict__ Zf,
    const float* __restrict__ bias, float* __restrict__ C) {
  __shared__ __align__(16) char smem[18432];
  ushort_t(*Ws)[72] = (ushort_t(*)[72])smem;           // [64][72]
  ushort_t(*Xs)[72] = (ushort_t(*)[72])(smem + 9216);  // [64][72]

  const int tid = threadIdx.x;
  const int w = tid >> 6, lane = tid & 63, quad = lane >> 4, l16 = lane & 15;
  const int o0 = blockIdx.y * 64, n0 = blockIdx.x * 64;
  const int lr = tid >> 2, lseg = (tid & 3) * 16;

  floatx4 acc[4];
#pragma unroll
  for (int ot = 0; ot < 4; ++ot) {
    acc[ot][0] = 0.f; acc[ot][1] = 0.f; acc[ot][2] = 0.f; acc[ot][3] = 0.f;
  }

  for (int k0 = 0; k0 < EDIM; k0 += 64) {
    const us8 w0 = *(const us8*)(Wf + (o0 + lr) * 512 + k0 + lseg);
    const us8 w1 = *(const us8*)(Wf + (o0 + lr) * 512 + k0 + lseg + 8);
    const us8 x0 = *(const us8*)(Zf + (n0 + lr) * 512 + k0 + lseg);
    const us8 x1 = *(const us8*)(Zf + (n0 + lr) * 512 + k0 + lseg + 8);
    __syncthreads();
    *(us8*)&Ws[lr][lseg] = w0;
    *(us8*)&Ws[lr][lseg + 8] = w1;
    *(us8*)&Xs[lr][lseg] = x0;
    *(us8*)&Xs[lr][lseg + 8] = x1;
    __syncthreads();

    half8 a[2][4], b[2];
#pragma unroll
    for (int kh = 0; kh < 2; ++kh) {
#pragma unroll
      for (int ot = 0; ot < 4; ++ot)
        a[kh][ot] = *(const half8*)&Ws[ot * 16 + l16][kh * 32 + quad * 8];
      b[kh] = *(const half8*)&Xs[w * 16 + l16][kh * 32 + quad * 8];
    }
#pragma unroll
    for (int kh = 0; kh < 2; ++kh)
#pragma unroll
      for (int ot = 0; ot < 4; ++ot)
        acc[ot] = __builtin_amdgcn_mfma_f32_16x16x32_f16(a[kh][ot], b[kh],
                                                         acc[ot], 0, 0, 0);
  }

  __syncthreads();
  float(*Cs)[68] = (float(*)[68])smem;
#pragma unroll
  for (int ot = 0; ot < 4; ++ot) {
    floatx4 v = acc[ot];
#pragma unroll
    for (int r = 0; r < 4; ++r) v[r] += bias[o0 + ot * 16 + quad * 4 + r];
    *(floatx4*)&Cs[w * 16 + l16][ot * 16 + quad * 4] = v;
  }
  __syncthreads();
  const int row = tid >> 2, seg = (tid & 3) * 16;
#pragma unroll
  for (int j = 0; j < 4; ++j)
    *(float4*)(C + (n0 + row) * 512 + o0 + seg + j * 4) =
        *(const float4*)&Cs[row][seg + j * 4];
}

// ---------------------------------------------------------------------------
// Flash attention, R24 = R20 + split qt loop: 32x32x16 f16 MFMA,
// transposed-score, double-buffered LDS K/V (one barrier/chunk, loads a
// full chunk ahead), max-free softmax, in-register P (cvt_pkrtz +
// v_permlane32_swap_b32), us8-granular f16 Z^T partials, split-K 4.
//   QK:  s = mfma32(kf, qf)    D[col=q=l32][row=m=(r&3)+8*(r>>2)+4*hi]
//   PV:  z = mfma32(vf, pa)    D[col=q=l32][row=d-local]
// Inner t-iteration: issue BOTH QK chains (qt=0,1) first, then both
// softmax+PV phases -- QK(q1) MFMAs execute under softmax(q0) VALU,
// PV(q0) overlaps softmax(q1).
// ---------------------------------------------------------------------------
__global__ __launch_bounds__(256, 2) void attn_mfma(
    const ushort_t* __restrict__ Qb, const ushort_t* __restrict__ Kb,
    const ushort_t* __restrict__ Vt, ushort_t* __restrict__ Zp,
    float* __restrict__ Lp) {
  __shared__ __align__(16) ushort_t Ks[2][128][72];    // K chunk [m][d]
  __shared__ __align__(16) ushort_t Vts[2][64][136];   // V^T chunk [d][m]

  const int tid = threadIdx.x;
  const int w = tid >> 6;
  const int lane = tid & 63;
  const int hi = lane >> 5;
  const int l32 = lane & 31;
  const int h = blockIdx.y;
  const int n0 = blockIdx.x * 256;
  const int z = blockIdx.z;
  const int mbase = z * (NSEQ / 4);

  // Q fragments: B-operand, B[col=q=l32][k=d=kk*16+hi*8+j]
  half8 qf[2][4];
#pragma unroll
  for (int qt = 0; qt < 2; ++qt) {
    const ushort_t* qsrc =
        Qb + h * 262144 + (n0 + w * 64 + qt * 32 + l32) * 64 + hi * 8;
#pragma unroll
    for (int kk = 0; kk < 4; ++kk)
      qf[qt][kk] = *(const half8*)(qsrc + kk * 16);
  }

  floatx16 zacc[2][2];
  float sl[2] = {0.f, 0.f};
#pragma unroll
  for (int qt = 0; qt < 2; ++qt)
#pragma unroll
    for (int dt = 0; dt < 2; ++dt)
#pragma unroll
      for (int r = 0; r < 16; ++r) zacc[qt][dt][r] = 0.f;

  const int kr = tid >> 2;
  const int kc = (tid & 3) << 4;
  const int vd = tid >> 2;
  const int vm = (tid & 3) << 5;
  const ushort_t* kbase = Kb + h * 262144 + mbase * 64;
  const ushort_t* vbase = Vt + h * 262144 + vd * 4096 + mbase + vm;

  us8 kst[4], vst[4];

#define LOADC(c)                                                       \
  {                                                                    \
    const ushort_t* ksrc = kbase + (c) * (128 * 64);                   \
    kst[0] = *(const us8*)(ksrc + kr * 64 + kc);                       \
    kst[1] = *(const us8*)(ksrc + kr * 64 + kc + 8);                   \
    kst[2] = *(const us8*)(ksrc + (64 + kr) * 64 + kc);                \
    kst[3] = *(const us8*)(ksrc + (64 + kr) * 64 + kc + 8);            \
    const ushort_t* vsrc = vbase + (c) * 128;                          \
    _Pragma("unroll") for (int j = 0; j < 4; ++j) vst[j] =             \
        *(const us8*)(vsrc + j * 8);                                   \
  }

#define STOREC(p)                                                      \
  {                                                                    \
    *(us8*)&Ks[p][kr][kc] = kst[0];                                    \
    *(us8*)&Ks[p][kr][kc + 8] = kst[1];                                \
    *(us8*)&Ks[p][64 + kr][kc] = kst[2];                               \
    *(us8*)&Ks[p][64 + kr][kc + 8] = kst[3];                           \
    _Pragma("unroll") for (int j = 0; j < 4; ++j)                      \
        *(us8*)&Vts[p][vd][vm + j * 8] = vst[j];                       \
  }

  LOADC(0);
  STOREC(0);
  LOADC(1);
  __syncthreads();

  for (int c = 0; c < 8; ++c) {
    const int p = c & 1;
    if (c < 7) {
      STOREC(p ^ 1);          // chunk c+1, regs loaded one full chunk ago
      if (c < 6) LOADC(c + 2);
    }

#pragma unroll
    for (int t = 0; t < 4; ++t) {
      // K fragments for this 32-key tile: A[row=m=t*32+l32][k=kk*16+hi*8+j]
      half8 kf[4];
#pragma unroll
      for (int kk = 0; kk < 4; ++kk)
        kf[kk] = *(const half8*)&Ks[p][t * 32 + l32][kk * 16 + hi * 8];
      // V^T fragments: A[row=d=dt*32+l32][k=m=mm*16+hi*8+j]
      half8 vf[2][2];
#pragma unroll
      for (int dt = 0; dt < 2; ++dt)
#pragma unroll
        for (int mm = 0; mm < 2; ++mm)
          vf[dt][mm] =
              *(const half8*)&Vts[p][dt * 32 + l32][t * 32 + mm * 16 + hi * 8];

      // ---- phase 1: BOTH QK chains issued back-to-back ----
      floatx16 s[2];
#pragma unroll
      for (int qt = 0; qt < 2; ++qt) {
#pragma unroll
        for (int r = 0; r < 16; ++r) s[qt][r] = 0.f;
#pragma unroll
        for (int kk = 0; kk < 4; ++kk)
          s[qt] = __builtin_amdgcn_mfma_f32_32x32x16_f16(kf[kk], qf[qt][kk],
                                                         s[qt], 0, 0, 0);
      }

      // ---- phase 2: softmax + PV per qt (overlaps the other qt's MFMAs) --
#pragma unroll
      for (int qt = 0; qt < 2; ++qt) {
        // lane (hi,l32) holds P[m=(r&3)+8*(r>>2)+4*hi][q=l32], r=0..15
        float e[16];
#pragma unroll
        for (int r = 0; r < 16; ++r) e[r] = EXP2F(s[qt][r]);
        sl[qt] += ((((e[0] + e[1]) + (e[2] + e[3])) +
                    ((e[4] + e[5]) + (e[6] + e[7]))) +
                   (((e[8] + e[9]) + (e[10] + e[11])) +
                    ((e[12] + e[13]) + (e[14] + e[15]))));
        // pack pairs (m, m+1) and build PV B-frags via lane<->lane+32 swap
        union { pkhalf2 hh; unsigned uu; } p01, p23, p45, p67, p89, pab, pcd, pef;
        p01.hh = __builtin_amdgcn_cvt_pkrtz(e[0], e[1]);
        p23.hh = __builtin_amdgcn_cvt_pkrtz(e[2], e[3]);
        p45.hh = __builtin_amdgcn_cvt_pkrtz(e[4], e[5]);
        p67.hh = __builtin_amdgcn_cvt_pkrtz(e[6], e[7]);
        p89.hh = __builtin_amdgcn_cvt_pkrtz(e[8], e[9]);
        pab.hh = __builtin_amdgcn_cvt_pkrtz(e[10], e[11]);
        pcd.hh = __builtin_amdgcn_cvt_pkrtz(e[12], e[13]);
        pef.hh = __builtin_amdgcn_cvt_pkrtz(e[14], e[15]);
        unsigned a0 = p01.uu, a1 = p23.uu, a2 = p45.uu, a3 = p67.uu;
        unsigned b0 = p89.uu, b1 = pab.uu, b2 = pcd.uu, b3 = pef.uu;
        // after swap: vdst = [own.lo | other.lo], vsrc = [other.hi | own.hi]
        asm("v_permlane32_swap_b32 %0, %1" : "+v"(a0), "+v"(a2));
        asm("v_permlane32_swap_b32 %0, %1" : "+v"(a1), "+v"(a3));
        asm("v_permlane32_swap_b32 %0, %1" : "+v"(b0), "+v"(b2));
        asm("v_permlane32_swap_b32 %0, %1" : "+v"(b1), "+v"(b3));
        union { half8 hh; unsigned uu[4]; } pa0, pa1;
        pa0.uu[0] = a0; pa0.uu[1] = a1; pa0.uu[2] = a2; pa0.uu[3] = a3;
        pa1.uu[0] = b0; pa1.uu[1] = b1; pa1.uu[2] = b2; pa1.uu[3] = b3;
#pragma unroll
        for (int dt = 0; dt < 2; ++dt) {
          zacc[qt][dt] = __builtin_amdgcn_mfma_f32_32x32x16_f16(
              vf[dt][0], pa0.hh, zacc[qt][dt], 0, 0, 0);
          zacc[qt][dt] = __builtin_amdgcn_mfma_f32_32x32x16_f16(
              vf[dt][1], pa1.hh, zacc[qt][dt], 0, 0, 0);
        }
      }
    }
    __syncthreads();
  }

  // ---- partial epilogue: Z^T partials as f16; rowsum via one shfl_xor ----
  // Per (dt, pair-of-d8-blocks): cvt_pkrtz 8 accs -> 4 words, 2
  // permlane32_swaps so lo-lane holds d 0..7 and hi-lane d 8..15 contiguous;
  // one aligned us8 store per lane => 32 contiguous B per row per instr.
#pragma unroll
  for (int qt = 0; qt < 2; ++qt) {
    float s = sl[qt];
    s += __shfl_xor(s, 32, 64);
    const int n = n0 + w * 64 + qt * 32 + l32;
    ushort_t* dst = Zp + z * 2097152 + n * EDIM + h * 64;
#pragma unroll
    for (int dt = 0; dt < 2; ++dt)
#pragma unroll
      for (int pr = 0; pr < 2; ++pr) {
        union { pkhalf2 hh; unsigned uu; } x0, x1, y0, y1;
        x0.hh = __builtin_amdgcn_cvt_pkrtz(zacc[qt][dt][pr * 8 + 0],
                                           zacc[qt][dt][pr * 8 + 1]);
        x1.hh = __builtin_amdgcn_cvt_pkrtz(zacc[qt][dt][pr * 8 + 2],
                                           zacc[qt][dt][pr * 8 + 3]);
        y0.hh = __builtin_amdgcn_cvt_pkrtz(zacc[qt][dt][pr * 8 + 4],
                                           zacc[qt][dt][pr * 8 + 5]);
        y1.hh = __builtin_amdgcn_cvt_pkrtz(zacc[qt][dt][pr * 8 + 6],
                                           zacc[qt][dt][pr * 8 + 7]);
        unsigned a0 = x0.uu, a1 = x1.uu, b0 = y0.uu, b1 = y1.uu;
        // lo lane: [d0,1 d2,3 | d4,5 d6,7]; hi lane: [d8,9 ... d14,15]
        asm("v_permlane32_swap_b32 %0, %1" : "+v"(a0), "+v"(b0));
        asm("v_permlane32_swap_b32 %0, %1" : "+v"(a1), "+v"(b1));
        union { us8 v; unsigned u[4]; } o;
        o.u[0] = a0; o.u[1] = a1; o.u[2] = b0; o.u[3] = b1;
        *(us8*)(dst + dt * 32 + pr * 16 + hi * 8) = o.v;
      }
    if (hi == 0) Lp[z * 32768 + h * 4096 + n] = s;
  }
}

extern "C" void kernel_launch(void* const* d_in, const int* in_sizes, int n_in,
                              void* d_out, int out_size, void* d_ws,
                              size_t ws_size, hipStream_t stream) {
  const float* inp = (const float*)d_in[0];
  const float* WKw = (const float*)d_in[1];
  const float* WKb = (const float*)d_in[2];
  const float* WQw = (const float*)d_in[3];
  const float* WQb = (const float*)d_in[4];
  const float* WVw = (const float*)d_in[5];
  const float* WVb = (const float*)d_in[6];
  const float* WZw = (const float*)d_in[7];
  const float* WZb = (const float*)d_in[8];

  char* ws = (char*)d_ws;
  const size_t MB = 1 << 20;
  ushort_t* Xf = (ushort_t*)(ws);                        // 4MB; Zf after attn
  ushort_t* WQf = (ushort_t*)(ws + 4 * MB);              // 512KB each
  ushort_t* WKf = (ushort_t*)(ws + 4 * MB + 512 * 1024);
  ushort_t* WVf = (ushort_t*)(ws + 5 * MB);
  ushort_t* WZf = (ushort_t*)(ws + 5 * MB + 512 * 1024);
  ushort_t* Qb = (ushort_t*)(ws + 6 * MB);    // 4MB f16 (E,N) scrambled, *C2
  ushort_t* Kb = (ushort_t*)(ws + 10 * MB);   // 4MB f16 (N,E)
  ushort_t* Vtb = (ushort_t*)(ws + 14 * MB);  // 4MB f16 [h][d][m]
  ushort_t* Zp = (ushort_t*)(ws + 18 * MB);   // 16MB: [4][4096][512] f16
  float* Lp = (float*)(ws + 34 * MB);         // 512KB: [4][8][4096]

  cast_all<<<3072, 256, 0, stream>>>(inp, Xf, WKw, WQw, WVw, WZw, WKf, WQf,
                                     WVf, WZf);

  gemm_qkv<<<dim3(NSEQ / 128, EDIM / 64, 3), 256, 0, stream>>>(
      WQf, WQb, WKf, WKb, WVf, WVb, Xf, Qb, Kb, Vtb);

  attn_mfma<<<dim3(NSEQ / 256, NHEAD, 4), 256, 0, stream>>>(Qb, Kb, Vtb, Zp,
                                                            Lp);

  combine<<<1024, 256, 0, stream>>>(Zp, Lp, Xf);  // Xf reused as Zf

  gemm_out<<<dim3(NSEQ / 64, EDIM / 64), 256, 0, stream>>>(WZf, Xf, WZb,
                                                           (float*)d_out);
}